// Round 1
// baseline (496.590 us; speedup 1.0000x reference)
//
#include <hip/hip_runtime.h>
#include <hip/hip_bf16.h>

// MoE experts, E=8 H=1024 I=4096 T=8192, f32 I/O, bf16 MFMA compute.
// Reassociation (no activation between GEMMs):
//   M_e = W1_e @ W2_e  (68.7 GF)   then   down = x @ M_e  (17.2 GF)
// Round-4 plan: occupancy. Round-3 counters showed wgemm at Occupancy 21.8%
// (grid 512 = 2 blocks/CU), MfmaUtil 18.6%, VALUBusy 7.4%, HBM 33% -- pure
// latency/barrier-bound. Fix: wgemm split-K x2 (1024 blocks = 4/CU, f32
// partials + tiny reduce), tgemm 64x128 tiles (1024 blocks = 4/CU, no extra
// passes). Inner m97 structure (glds width-16, 16x16x32 bf16 MFMA) unchanged.

typedef unsigned short u16;
typedef unsigned int u32;
typedef __attribute__((ext_vector_type(8))) short bf16x8;   // 8 bf16 = 4 VGPR
typedef __attribute__((ext_vector_type(4))) float f32x4;
typedef __attribute__((ext_vector_type(4))) u32 u32x4;

#define E_N 8
#define H_N 1024
#define I_N 4096
#define T_N 8192

// async global->LDS, 16B/lane; LDS dest is wave-uniform base + lane*16
#define GLD2LDS16(g, l)                                                        \
  __builtin_amdgcn_global_load_lds(                                            \
      (const __attribute__((address_space(1))) void*)(g),                      \
      (__attribute__((address_space(3))) void*)(l), 16, 0, 0)

// pack two f32 -> (lo,hi) bf16 pair, round-to-nearest (+0x8000, v_perm)
__device__ __forceinline__ u32 pkbf(float lo, float hi) {
  u32 a = __float_as_uint(lo) + 0x8000u;
  u32 b = __float_as_uint(hi) + 0x8000u;
  return __builtin_amdgcn_perm(b, a, 0x07060302u);
}

__device__ __forceinline__ u16 f2bf(float f) {
  __hip_bfloat16 h = __float2bfloat16(f);
  return *(reinterpret_cast<u16*>(&h));
}

// ---------------------------------------------------------------------------
// Elementwise f32 -> bf16, 8 elems/thread (2x float4 in, 1x 16B out)
// ---------------------------------------------------------------------------
__global__ __launch_bounds__(256) void cvt_kernel(const float* __restrict__ src,
                                                  u16* __restrict__ dst) {
  const size_t i = ((size_t)blockIdx.x * 256 + threadIdx.x) * 8;
  float4 a = *(const float4*)(src + i);
  float4 b = *(const float4*)(src + i + 4);
  *(u32x4*)(dst + i) = (u32x4){pkbf(a.x, a.y), pkbf(a.z, a.w),
                               pkbf(b.x, b.y), pkbf(b.z, b.w)};
}

// ---------------------------------------------------------------------------
// W2 [E][I][H] f32  ->  W2T [E][H][I] bf16.  64x64 tiles via LDS (pad 65).
// grid (16 h-tiles, 64 i-tiles, 8 experts), 256 threads.
// ---------------------------------------------------------------------------
__global__ __launch_bounds__(256) void transp_kernel(const float* __restrict__ w2,
                                                     u16* __restrict__ w2t) {
  __shared__ float tile[64 * 65];
  const int tid = threadIdx.x;
  const int h0 = blockIdx.x * 64;
  const int i0 = blockIdx.y * 64;
  const float* src = w2 + (size_t)blockIdx.z * I_N * H_N;
  u16* dst = w2t + (size_t)blockIdx.z * H_N * I_N;

  // load: 4 passes of 16 rows; row-coalesced float4, scalar LDS stores
  {
    const int r = tid >> 4;          // 0..15
    const int c4 = (tid & 15) * 4;   // 0..60
#pragma unroll
    for (int rr = 0; rr < 4; rr++) {
      const int row = rr * 16 + r;
      float4 v = *(const float4*)(src + (size_t)(i0 + row) * H_N + h0 + c4);
      tile[row * 65 + c4 + 0] = v.x;
      tile[row * 65 + c4 + 1] = v.y;
      tile[row * 65 + c4 + 2] = v.z;
      tile[row * 65 + c4 + 3] = v.w;
    }
  }
  __syncthreads();

  // store: h = hh*32 + tid>>3, i-chunk = (tid&7)*8; 2-way-free LDS reads,
  // per-wave 8 rows x 128B contiguous global stores
  {
    const int hr = tid >> 3;        // 0..31
    const int ic = (tid & 7) * 8;   // 0..56
#pragma unroll
    for (int hh = 0; hh < 2; hh++) {
      const int h = hh * 32 + hr;
      u32 p[4];
#pragma unroll
      for (int j = 0; j < 4; j++)
        p[j] = pkbf(tile[(ic + 2 * j) * 65 + h], tile[(ic + 2 * j + 1) * 65 + h]);
      *(u32x4*)(dst + (size_t)(h0 + h) * I_N + i0 + ic) =
          (u32x4){p[0], p[1], p[2], p[3]};
    }
  }
}

// ---------------------------------------------------------------------------
// Weight GEMM fallback (no split-K): Mt[e][h2][h1] = sum_i W2T[e][h2][i]*W1b[e][h1][i]
// Tile 128x128, BK=32, 256 threads (2x2 waves of 64x64). Used only if the
// workspace is too small for split-K partials.
// ---------------------------------------------------------------------------
__global__ __launch_bounds__(256) void wgemm_kernel(const u16* __restrict__ w2t,
                                                    const u16* __restrict__ w1b,
                                                    u16* __restrict__ mt) {
  __shared__ u16 ldsA[4096];  // [m:128][k:32]
  __shared__ u16 ldsB[4096];  // [n:128][k:32]

  const int tid = threadIdx.x;
  const int lane = tid & 63;
  const int wv = tid >> 6;
  const int wm = wv >> 1, wn = wv & 1;
  const int lm = lane & 15, quad = lane >> 4;

  const int e = blockIdx.x >> 6;
  const int t = blockIdx.x & 63;
  const int row0 = (t >> 3) * 128;  // h2
  const int col0 = (t & 7) * 128;   // h1

  const u16* Ae = w2t + (size_t)e * H_N * I_N;
  const u16* Be = w1b + (size_t)e * H_N * I_N;
  u16* mte = mt + (size_t)e * H_N * H_N;

  const int s_r = tid >> 2;
  const int s_k = (tid & 3) * 8;
  const u16* gA0 = Ae + (size_t)(row0 + s_r) * I_N + s_k;
  const u16* gA1 = gA0 + (size_t)64 * I_N;
  const u16* gB0 = Be + (size_t)(col0 + s_r) * I_N + s_k;
  const u16* gB1 = gB0 + (size_t)64 * I_N;
  u16* ldsA_dst = ldsA + wv * 512;  // wave-uniform; HW appends lane*16B
  u16* ldsB_dst = ldsB + wv * 512;

  f32x4 acc[4][4];
#pragma unroll
  for (int i = 0; i < 4; i++)
#pragma unroll
    for (int j = 0; j < 4; j++) acc[i][j] = (f32x4){0.f, 0.f, 0.f, 0.f};

  for (int k0 = 0; k0 < I_N; k0 += 32) {
    GLD2LDS16(gA0 + k0, ldsA_dst);
    GLD2LDS16(gA1 + k0, ldsA_dst + 2048);
    GLD2LDS16(gB0 + k0, ldsB_dst);
    GLD2LDS16(gB1 + k0, ldsB_dst + 2048);

    __syncthreads();

    bf16x8 af[4], bfr[4];
#pragma unroll
    for (int mi = 0; mi < 4; mi++)
      af[mi] = *(const bf16x8*)(ldsA + (wm * 64 + mi * 16 + lm) * 32 + quad * 8);
#pragma unroll
    for (int ni = 0; ni < 4; ni++)
      bfr[ni] = *(const bf16x8*)(ldsB + (wn * 64 + ni * 16 + lm) * 32 + quad * 8);
#pragma unroll
    for (int mi = 0; mi < 4; mi++)
#pragma unroll
      for (int ni = 0; ni < 4; ni++)
        acc[mi][ni] = __builtin_amdgcn_mfma_f32_16x16x32_bf16(
            af[mi], bfr[ni], acc[mi][ni], 0, 0, 0);

    __syncthreads();
  }

  // C/D: col = lane&15, row = quad*4 + reg
  const int orow = row0 + wm * 64 + quad * 4;
  const int ocol = col0 + wn * 64 + lm;
#pragma unroll
  for (int mi = 0; mi < 4; mi++)
#pragma unroll
    for (int ni = 0; ni < 4; ni++)
#pragma unroll
      for (int r = 0; r < 4; r++)
        mte[(size_t)(orow + mi * 16 + r) * H_N + ocol + ni * 16] =
            f2bf(acc[mi][ni][r]);
}

// ---------------------------------------------------------------------------
// Weight GEMM, split-K x2: 1024 blocks (kh in [0,2), e in [0,8), 64 tiles).
// Each block sums k in [kh*2048, kh*2048+2048); f32 partials to mtp.
// Same 128x128 / BK=32 / 2x2-wave inner structure as wgemm_kernel.
// ---------------------------------------------------------------------------
__global__ __launch_bounds__(256) void wgemm_split_kernel(
    const u16* __restrict__ w2t, const u16* __restrict__ w1b,
    float* __restrict__ mtp) {
  __shared__ u16 ldsA[4096];  // [m:128][k:32]
  __shared__ u16 ldsB[4096];  // [n:128][k:32]

  const int tid = threadIdx.x;
  const int lane = tid & 63;
  const int wv = tid >> 6;
  const int wm = wv >> 1, wn = wv & 1;
  const int lm = lane & 15, quad = lane >> 4;

  const int kh = blockIdx.x >> 9;        // 0..1
  const int bi = blockIdx.x & 511;
  const int e = bi >> 6;
  const int t = bi & 63;
  const int row0 = (t >> 3) * 128;  // h2
  const int col0 = (t & 7) * 128;   // h1

  const u16* Ae = w2t + (size_t)e * H_N * I_N;
  const u16* Be = w1b + (size_t)e * H_N * I_N;

  const int s_r = tid >> 2;
  const int s_k = (tid & 3) * 8;
  const u16* gA0 = Ae + (size_t)(row0 + s_r) * I_N + s_k;
  const u16* gA1 = gA0 + (size_t)64 * I_N;
  const u16* gB0 = Be + (size_t)(col0 + s_r) * I_N + s_k;
  const u16* gB1 = gB0 + (size_t)64 * I_N;
  u16* ldsA_dst = ldsA + wv * 512;
  u16* ldsB_dst = ldsB + wv * 512;

  f32x4 acc[4][4];
#pragma unroll
  for (int i = 0; i < 4; i++)
#pragma unroll
    for (int j = 0; j < 4; j++) acc[i][j] = (f32x4){0.f, 0.f, 0.f, 0.f};

  const int kbeg = kh * (I_N / 2);
  for (int k0 = kbeg; k0 < kbeg + I_N / 2; k0 += 32) {
    GLD2LDS16(gA0 + k0, ldsA_dst);
    GLD2LDS16(gA1 + k0, ldsA_dst + 2048);
    GLD2LDS16(gB0 + k0, ldsB_dst);
    GLD2LDS16(gB1 + k0, ldsB_dst + 2048);

    __syncthreads();

    bf16x8 af[4], bfr[4];
#pragma unroll
    for (int mi = 0; mi < 4; mi++)
      af[mi] = *(const bf16x8*)(ldsA + (wm * 64 + mi * 16 + lm) * 32 + quad * 8);
#pragma unroll
    for (int ni = 0; ni < 4; ni++)
      bfr[ni] = *(const bf16x8*)(ldsB + (wn * 64 + ni * 16 + lm) * 32 + quad * 8);
#pragma unroll
    for (int mi = 0; mi < 4; mi++)
#pragma unroll
      for (int ni = 0; ni < 4; ni++)
        acc[mi][ni] = __builtin_amdgcn_mfma_f32_16x16x32_bf16(
            af[mi], bfr[ni], acc[mi][ni], 0, 0, 0);

    __syncthreads();
  }

  float* dst = mtp + ((size_t)(kh * E_N + e)) * H_N * H_N;
  const int orow = row0 + wm * 64 + quad * 4;
  const int ocol = col0 + wn * 64 + lm;
#pragma unroll
  for (int mi = 0; mi < 4; mi++)
#pragma unroll
    for (int ni = 0; ni < 4; ni++)
#pragma unroll
      for (int r = 0; r < 4; r++)
        dst[(size_t)(orow + mi * 16 + r) * H_N + ocol + ni * 16] =
            acc[mi][ni][r];
}

// ---------------------------------------------------------------------------
// mt[i] = bf16(mtp_half0[i] + mtp_half1[i]); 8 elems/thread.
// ---------------------------------------------------------------------------
__global__ __launch_bounds__(256) void reduce_mt_kernel(
    const float* __restrict__ mtp, u16* __restrict__ mt) {
  const size_t i = ((size_t)blockIdx.x * 256 + threadIdx.x) * 8;
  const float* p0 = mtp + i;
  const float* p1 = mtp + (size_t)E_N * H_N * H_N + i;
  float4 a0 = *(const float4*)p0;
  float4 a1 = *(const float4*)(p0 + 4);
  float4 b0 = *(const float4*)p1;
  float4 b1 = *(const float4*)(p1 + 4);
  *(u32x4*)(mt + i) =
      (u32x4){pkbf(a0.x + b0.x, a0.y + b0.y), pkbf(a0.z + b0.z, a0.w + b0.w),
              pkbf(a1.x + b1.x, a1.y + b1.y), pkbf(a1.z + b1.z, a1.w + b1.w)};
}

// ---------------------------------------------------------------------------
// Token GEMM: out[t][h2] = sum_h1 xb[t][h1] * Mt[e(t)][h2][h1]
// Round-4: 64x128 tile (1024 blocks = 4 blocks/CU), BK=32, 256 threads
// (2x2 waves of 32x64). Output f32.
// ---------------------------------------------------------------------------
__global__ __launch_bounds__(256) void tgemm_kernel(const u16* __restrict__ xb,
                                                    const int* __restrict__ bsz,
                                                    const u16* __restrict__ mt,
                                                    float* __restrict__ out) {
  __shared__ u16 ldsA[2048];  // x tile  [m:64][k:32]
  __shared__ u16 ldsB[4096];  // Mt tile [n:128][k:32]

  const int tid = threadIdx.x;
  const int lane = tid & 63;
  const int wv = tid >> 6;
  const int wm = wv >> 1, wn = wv & 1;
  const int lm = lane & 15, quad = lane >> 4;

  const int bm = blockIdx.x >> 3, bn = blockIdx.x & 7;
  const int row0 = bm * 64;   // token
  const int col0 = bn * 128;  // h2

  int e = 0, start = 0;
#pragma unroll
  for (int i = 0; i < E_N; i++) {
    int b = bsz[i];
    if (row0 >= start + b) { start += b; e = i + 1; }
  }
  const u16* mte = mt + (size_t)e * H_N * H_N;

  const int s_r = tid >> 2;      // 0..63
  const int s_k = (tid & 3) * 8;
  const u16* gA0 = xb + (size_t)(row0 + s_r) * H_N + s_k;
  const u16* gB0 = mte + (size_t)(col0 + s_r) * H_N + s_k;
  const u16* gB1 = gB0 + (size_t)64 * H_N;
  u16* ldsA_dst = ldsA + wv * 512;  // wave w stages A rows [16w,16w+16)
  u16* ldsB_dst = ldsB + wv * 512;

  f32x4 acc[2][4];
#pragma unroll
  for (int i = 0; i < 2; i++)
#pragma unroll
    for (int j = 0; j < 4; j++) acc[i][j] = (f32x4){0.f, 0.f, 0.f, 0.f};

  for (int k0 = 0; k0 < H_N; k0 += 32) {
    GLD2LDS16(gA0 + k0, ldsA_dst);
    GLD2LDS16(gB0 + k0, ldsB_dst);
    GLD2LDS16(gB1 + k0, ldsB_dst + 2048);

    __syncthreads();

    bf16x8 af[2], bfr[4];
#pragma unroll
    for (int mi = 0; mi < 2; mi++)
      af[mi] = *(const bf16x8*)(ldsA + (wm * 32 + mi * 16 + lm) * 32 + quad * 8);
#pragma unroll
    for (int ni = 0; ni < 4; ni++)
      bfr[ni] = *(const bf16x8*)(ldsB + (wn * 64 + ni * 16 + lm) * 32 + quad * 8);
#pragma unroll
    for (int mi = 0; mi < 2; mi++)
#pragma unroll
      for (int ni = 0; ni < 4; ni++)
        acc[mi][ni] = __builtin_amdgcn_mfma_f32_16x16x32_bf16(
            af[mi], bfr[ni], acc[mi][ni], 0, 0, 0);

    __syncthreads();
  }

  const int orow = row0 + wm * 32 + quad * 4;
  const int ocol = col0 + wn * 64 + lm;
#pragma unroll
  for (int mi = 0; mi < 2; mi++)
#pragma unroll
    for (int ni = 0; ni < 4; ni++)
#pragma unroll
      for (int r = 0; r < 4; r++)
        out[(size_t)(orow + mi * 16 + r) * H_N + ocol + ni * 16] =
            acc[mi][ni][r];
}

extern "C" void kernel_launch(void* const* d_in, const int* in_sizes, int n_in,
                              void* d_out, int out_size, void* d_ws,
                              size_t ws_size, hipStream_t stream) {
  (void)in_sizes; (void)n_in; (void)out_size;
  const float* hiddens = (const float*)d_in[0];
  const int* bsz = (const int*)d_in[1];
  const float* w1 = (const float*)d_in[2];
  const float* w2 = (const float*)d_in[3];
  float* out = (float*)d_out;

  // workspace layout (MiB): w1b 0:64 | w2t 64:128 | xb 128:144 | mt 144:160
  //                       | mtp (f32 split-K partials) 160:224
  char* ws = (char*)d_ws;
  u16* w1b = (u16*)(ws);
  u16* w2t = (u16*)(ws + (size_t)64 * 1024 * 1024);
  u16* xb  = (u16*)(ws + (size_t)128 * 1024 * 1024);
  u16* mt  = (u16*)(ws + (size_t)144 * 1024 * 1024);
  float* mtp = (float*)(ws + (size_t)160 * 1024 * 1024);
  const bool splitw = ws_size >= (size_t)224 * 1024 * 1024;

  // pre-pass: bf16 conversions (+ W2 transpose)
  cvt_kernel<<<dim3(16384), 256, 0, stream>>>(w1, w1b);          // W1: 33.5M elems
  cvt_kernel<<<dim3(4096), 256, 0, stream>>>(hiddens, xb);       // x: 8.4M elems
  transp_kernel<<<dim3(16, 64, E_N), 256, 0, stream>>>(w2, w2t);

  // M^T per expert
  if (splitw) {
    // split-K x2: 4 blocks/CU; f32 partials, then reduce+convert to bf16
    wgemm_split_kernel<<<dim3(1024), 256, 0, stream>>>(w2t, w1b, mtp);
    reduce_mt_kernel<<<dim3(4096), 256, 0, stream>>>(mtp, mt);
  } else {
    wgemm_kernel<<<dim3(512), 256, 0, stream>>>(w2t, w1b, mt);
  }

  // down = x @ M  (64x128 tiles -> 1024 blocks = 4 blocks/CU)
  tgemm_kernel<<<dim3(1024), 256, 0, stream>>>(xb, bsz, mt, out);
}

// Round 3
// 463.161 us; speedup vs baseline: 1.0722x; 1.0722x over previous
//
#include <hip/hip_runtime.h>
#include <hip/hip_bf16.h>

// MoE experts, E=8 H=1024 I=4096 T=8192, f32 I/O, bf16 MFMA compute.
// Reassociation (no activation between GEMMs):
//   M_e = W1_e @ W2_e  (68.7 GF)   then   down = x @ M_e  (17.2 GF)
// Round-5 plan: locality. Round-4 counters: wgemm_split FETCH 405 MB vs
// 128 MiB ideal (3x HBM over-fetch), MfmaUtil 20%, occupancy fix alone was
// neutral -> HBM-latency-bound through the vmcnt(0) barrier drain, because
// (a) f32 sources + partials thrash the 256 MiB LLC, (b) no XCD swizzle so
// panel reuse misses the per-XCD L2. Fix: T1 chunked XCD swizzle on both
// GEMMs, nontemporal loads for the once-read f32 sources, nontemporal
// stores for split-K partials + final out, fused single-dispatch pre-pass,
// split-K x4 when workspace allows (runtime fallback x2 / x1).
// Round-5b: nontemporal builtins need ext-vector types, not HIP float4.

typedef unsigned short u16;
typedef unsigned int u32;
typedef __attribute__((ext_vector_type(8))) short bf16x8;   // 8 bf16 = 4 VGPR
typedef __attribute__((ext_vector_type(4))) float f32x4;
typedef __attribute__((ext_vector_type(4))) u32 u32x4;

#define E_N 8
#define H_N 1024
#define I_N 4096
#define T_N 8192

// async global->LDS, 16B/lane; LDS dest is wave-uniform base + lane*16
#define GLD2LDS16(g, l)                                                        \
  __builtin_amdgcn_global_load_lds(                                            \
      (const __attribute__((address_space(1))) void*)(g),                      \
      (__attribute__((address_space(3))) void*)(l), 16, 0, 0)

// pack two f32 -> (lo,hi) bf16 pair, round-to-nearest (+0x8000, v_perm)
__device__ __forceinline__ u32 pkbf(float lo, float hi) {
  u32 a = __float_as_uint(lo) + 0x8000u;
  u32 b = __float_as_uint(hi) + 0x8000u;
  return __builtin_amdgcn_perm(b, a, 0x07060302u);
}

__device__ __forceinline__ u16 f2bf(float f) {
  __hip_bfloat16 h = __float2bfloat16(f);
  return *(reinterpret_cast<u16*>(&h));
}

// nontemporal 16B f32 load via ext-vector type (builtin rejects HIP float4)
__device__ __forceinline__ f32x4 ntload4(const float* p) {
  return __builtin_nontemporal_load((const f32x4*)p);
}

// T1: bijective chunked XCD swizzle (nwg % 8 == 0). Default dispatch
// round-robins blocks across the 8 XCDs; this gives each XCD a contiguous
// chunk so tiles sharing A/B panels hit the same per-XCD L2.
__device__ __forceinline__ int xcd_swz(int bid, int nwg) {
  const int chunk = nwg >> 3;
  return (bid & 7) * chunk + (bid >> 3);
}

// ---------------------------------------------------------------------------
// Fused pre-pass, one dispatch:
//   bid [0,16384)        : W1  f32 -> bf16      (w1b), nt loads
//   bid [16384,20480)    : x   f32 -> bf16      (xb),  nt loads
//   bid [20480,28672)    : W2  f32 -> bf16^T    (w2t), nt loads, LDS 64x65
// ---------------------------------------------------------------------------
#define NB_W1 16384
#define NB_X 4096
#define NB_TR 8192

__global__ __launch_bounds__(256) void prepass_kernel(
    const float* __restrict__ w1, const float* __restrict__ x,
    const float* __restrict__ w2, u16* __restrict__ w1b,
    u16* __restrict__ xb, u16* __restrict__ w2t) {
  __shared__ float tile[64 * 65];
  const int tid = threadIdx.x;
  const int bid = blockIdx.x;

  if (bid < NB_W1 + NB_X) {
    // elementwise cvt, 8 elems/thread
    const float* src;
    u16* dst;
    size_t base;
    if (bid < NB_W1) {
      src = w1; dst = w1b; base = (size_t)bid * 2048;
    } else {
      src = x; dst = xb; base = (size_t)(bid - NB_W1) * 2048;
    }
    const size_t i = base + (size_t)tid * 8;
    f32x4 a = ntload4(src + i);
    f32x4 b = ntload4(src + i + 4);
    *(u32x4*)(dst + i) = (u32x4){pkbf(a.x, a.y), pkbf(a.z, a.w),
                                 pkbf(b.x, b.y), pkbf(b.z, b.w)};
    return;
  }

  // W2 [E][I][H] f32 -> W2T [E][H][I] bf16, 64x64 tiles (pad 65)
  const int b = bid - (NB_W1 + NB_X);
  const int e = b >> 10;          // 16*64 tiles per expert
  const int rem = b & 1023;
  const int i0 = (rem >> 4) * 64; // i-tile
  const int h0 = (rem & 15) * 64; // h-tile
  const float* src = w2 + (size_t)e * I_N * H_N;
  u16* dst = w2t + (size_t)e * H_N * I_N;

  // load: 4 passes of 16 rows; row-coalesced f32x4 (nt), scalar LDS stores
  {
    const int r = tid >> 4;          // 0..15
    const int c4 = (tid & 15) * 4;   // 0..60
#pragma unroll
    for (int rr = 0; rr < 4; rr++) {
      const int row = rr * 16 + r;
      f32x4 v = ntload4(src + (size_t)(i0 + row) * H_N + h0 + c4);
      tile[row * 65 + c4 + 0] = v.x;
      tile[row * 65 + c4 + 1] = v.y;
      tile[row * 65 + c4 + 2] = v.z;
      tile[row * 65 + c4 + 3] = v.w;
    }
  }
  __syncthreads();

  // store: 2-way-free LDS reads, per-wave 8 rows x 128B contiguous stores
  {
    const int hr = tid >> 3;        // 0..31
    const int ic = (tid & 7) * 8;   // 0..56
#pragma unroll
    for (int hh = 0; hh < 2; hh++) {
      const int h = hh * 32 + hr;
      u32 p[4];
#pragma unroll
      for (int j = 0; j < 4; j++)
        p[j] = pkbf(tile[(ic + 2 * j) * 65 + h], tile[(ic + 2 * j + 1) * 65 + h]);
      *(u32x4*)(dst + (size_t)(h0 + h) * I_N + i0 + ic) =
          (u32x4){p[0], p[1], p[2], p[3]};
    }
  }
}

// ---------------------------------------------------------------------------
// Weight GEMM fallback (no split-K): Mt[e][h2][h1] = sum_i W2T[e][h2][i]*W1b[e][h1][i]
// Tile 128x128, BK=32, 256 threads (2x2 waves of 64x64). Used only if the
// workspace is too small for split-K partials.
// ---------------------------------------------------------------------------
__global__ __launch_bounds__(256) void wgemm_kernel(const u16* __restrict__ w2t,
                                                    const u16* __restrict__ w1b,
                                                    u16* __restrict__ mt) {
  __shared__ u16 ldsA[4096];  // [m:128][k:32]
  __shared__ u16 ldsB[4096];  // [n:128][k:32]

  const int tid = threadIdx.x;
  const int lane = tid & 63;
  const int wv = tid >> 6;
  const int wm = wv >> 1, wn = wv & 1;
  const int lm = lane & 15, quad = lane >> 4;

  const int sbid = xcd_swz(blockIdx.x, 512);
  const int e = sbid >> 6;
  const int t = sbid & 63;
  const int row0 = (t >> 3) * 128;  // h2
  const int col0 = (t & 7) * 128;   // h1

  const u16* Ae = w2t + (size_t)e * H_N * I_N;
  const u16* Be = w1b + (size_t)e * H_N * I_N;
  u16* mte = mt + (size_t)e * H_N * H_N;

  const int s_r = tid >> 2;
  const int s_k = (tid & 3) * 8;
  const u16* gA0 = Ae + (size_t)(row0 + s_r) * I_N + s_k;
  const u16* gA1 = gA0 + (size_t)64 * I_N;
  const u16* gB0 = Be + (size_t)(col0 + s_r) * I_N + s_k;
  const u16* gB1 = gB0 + (size_t)64 * I_N;
  u16* ldsA_dst = ldsA + wv * 512;  // wave-uniform; HW appends lane*16B
  u16* ldsB_dst = ldsB + wv * 512;

  f32x4 acc[4][4];
#pragma unroll
  for (int i = 0; i < 4; i++)
#pragma unroll
    for (int j = 0; j < 4; j++) acc[i][j] = (f32x4){0.f, 0.f, 0.f, 0.f};

  for (int k0 = 0; k0 < I_N; k0 += 32) {
    GLD2LDS16(gA0 + k0, ldsA_dst);
    GLD2LDS16(gA1 + k0, ldsA_dst + 2048);
    GLD2LDS16(gB0 + k0, ldsB_dst);
    GLD2LDS16(gB1 + k0, ldsB_dst + 2048);

    __syncthreads();

    bf16x8 af[4], bfr[4];
#pragma unroll
    for (int mi = 0; mi < 4; mi++)
      af[mi] = *(const bf16x8*)(ldsA + (wm * 64 + mi * 16 + lm) * 32 + quad * 8);
#pragma unroll
    for (int ni = 0; ni < 4; ni++)
      bfr[ni] = *(const bf16x8*)(ldsB + (wn * 64 + ni * 16 + lm) * 32 + quad * 8);
#pragma unroll
    for (int mi = 0; mi < 4; mi++)
#pragma unroll
      for (int ni = 0; ni < 4; ni++)
        acc[mi][ni] = __builtin_amdgcn_mfma_f32_16x16x32_bf16(
            af[mi], bfr[ni], acc[mi][ni], 0, 0, 0);

    __syncthreads();
  }

  // C/D: col = lane&15, row = quad*4 + reg
  const int orow = row0 + wm * 64 + quad * 4;
  const int ocol = col0 + wn * 64 + lm;
#pragma unroll
  for (int mi = 0; mi < 4; mi++)
#pragma unroll
    for (int ni = 0; ni < 4; ni++)
#pragma unroll
      for (int r = 0; r < 4; r++)
        mte[(size_t)(orow + mi * 16 + r) * H_N + ocol + ni * 16] =
            f2bf(acc[mi][ni][r]);
}

// ---------------------------------------------------------------------------
// Weight GEMM, split-K x KSPLIT: grid 512*KSPLIT with T1 swizzle.
// Each block sums k over a I_N/KSPLIT segment; f32 partials (nt stores)
// to mtp[kh][e][h2][h1]. Same 128x128 / BK=32 inner structure.
// ---------------------------------------------------------------------------
template <int KSPLIT>
__global__ __launch_bounds__(256) void wgemm_split_kernel(
    const u16* __restrict__ w2t, const u16* __restrict__ w1b,
    float* __restrict__ mtp) {
  __shared__ u16 ldsA[4096];  // [m:128][k:32]
  __shared__ u16 ldsB[4096];  // [n:128][k:32]

  const int tid = threadIdx.x;
  const int lane = tid & 63;
  const int wv = tid >> 6;
  const int wm = wv >> 1, wn = wv & 1;
  const int lm = lane & 15, quad = lane >> 4;

  const int sbid = xcd_swz(blockIdx.x, 512 * KSPLIT);
  const int kh = sbid >> 9;         // 0..KSPLIT-1
  const int bi = sbid & 511;
  const int e = bi >> 6;
  const int t = bi & 63;
  const int row0 = (t >> 3) * 128;  // h2
  const int col0 = (t & 7) * 128;   // h1

  const u16* Ae = w2t + (size_t)e * H_N * I_N;
  const u16* Be = w1b + (size_t)e * H_N * I_N;

  const int s_r = tid >> 2;
  const int s_k = (tid & 3) * 8;
  const u16* gA0 = Ae + (size_t)(row0 + s_r) * I_N + s_k;
  const u16* gA1 = gA0 + (size_t)64 * I_N;
  const u16* gB0 = Be + (size_t)(col0 + s_r) * I_N + s_k;
  const u16* gB1 = gB0 + (size_t)64 * I_N;
  u16* ldsA_dst = ldsA + wv * 512;
  u16* ldsB_dst = ldsB + wv * 512;

  f32x4 acc[4][4];
#pragma unroll
  for (int i = 0; i < 4; i++)
#pragma unroll
    for (int j = 0; j < 4; j++) acc[i][j] = (f32x4){0.f, 0.f, 0.f, 0.f};

  const int KSEG = I_N / KSPLIT;
  const int kbeg = kh * KSEG;
  for (int k0 = kbeg; k0 < kbeg + KSEG; k0 += 32) {
    GLD2LDS16(gA0 + k0, ldsA_dst);
    GLD2LDS16(gA1 + k0, ldsA_dst + 2048);
    GLD2LDS16(gB0 + k0, ldsB_dst);
    GLD2LDS16(gB1 + k0, ldsB_dst + 2048);

    __syncthreads();

    bf16x8 af[4], bfr[4];
#pragma unroll
    for (int mi = 0; mi < 4; mi++)
      af[mi] = *(const bf16x8*)(ldsA + (wm * 64 + mi * 16 + lm) * 32 + quad * 8);
#pragma unroll
    for (int ni = 0; ni < 4; ni++)
      bfr[ni] = *(const bf16x8*)(ldsB + (wn * 64 + ni * 16 + lm) * 32 + quad * 8);
#pragma unroll
    for (int mi = 0; mi < 4; mi++)
#pragma unroll
      for (int ni = 0; ni < 4; ni++)
        acc[mi][ni] = __builtin_amdgcn_mfma_f32_16x16x32_bf16(
            af[mi], bfr[ni], acc[mi][ni], 0, 0, 0);

    __syncthreads();
  }

  // nt stores: partials are read exactly once by reduce; keep them out of
  // the LLC so the bf16 weights stay resident for other in-flight blocks.
  float* dst = mtp + ((size_t)(kh * E_N + e)) * H_N * H_N;
  const int orow = row0 + wm * 64 + quad * 4;
  const int ocol = col0 + wn * 64 + lm;
#pragma unroll
  for (int mi = 0; mi < 4; mi++)
#pragma unroll
    for (int ni = 0; ni < 4; ni++)
#pragma unroll
      for (int r = 0; r < 4; r++)
        __builtin_nontemporal_store(
            acc[mi][ni][r],
            dst + (size_t)(orow + mi * 16 + r) * H_N + ocol + ni * 16);
}

// ---------------------------------------------------------------------------
// mt[i] = bf16(sum_p mtp[p][i]); 8 elems/thread, nt loads.
// ---------------------------------------------------------------------------
template <int KSPLIT>
__global__ __launch_bounds__(256) void reduce_mt_kernel(
    const float* __restrict__ mtp, u16* __restrict__ mt) {
  const size_t i = ((size_t)blockIdx.x * 256 + threadIdx.x) * 8;
  float s[8];
#pragma unroll
  for (int j = 0; j < 8; j++) s[j] = 0.f;
#pragma unroll
  for (int p = 0; p < KSPLIT; p++) {
    const float* q = mtp + (size_t)p * E_N * H_N * H_N + i;
    f32x4 a = ntload4(q);
    f32x4 b = ntload4(q + 4);
    s[0] += a.x; s[1] += a.y; s[2] += a.z; s[3] += a.w;
    s[4] += b.x; s[5] += b.y; s[6] += b.z; s[7] += b.w;
  }
  *(u32x4*)(mt + i) = (u32x4){pkbf(s[0], s[1]), pkbf(s[2], s[3]),
                              pkbf(s[4], s[5]), pkbf(s[6], s[7])};
}

// ---------------------------------------------------------------------------
// Token GEMM: out[t][h2] = sum_h1 xb[t][h1] * Mt[e(t)][h2][h1]
// 64x128 tile (1024 blocks = 4 blocks/CU, T1 swizzle), BK=32, 256 threads
// (2x2 waves of 32x64). Output f32 (nt stores, never re-read).
// ---------------------------------------------------------------------------
__global__ __launch_bounds__(256) void tgemm_kernel(const u16* __restrict__ xb,
                                                    const int* __restrict__ bsz,
                                                    const u16* __restrict__ mt,
                                                    float* __restrict__ out) {
  __shared__ u16 ldsA[2048];  // x tile  [m:64][k:32]
  __shared__ u16 ldsB[4096];  // Mt tile [n:128][k:32]

  const int tid = threadIdx.x;
  const int lane = tid & 63;
  const int wv = tid >> 6;
  const int wm = wv >> 1, wn = wv & 1;
  const int lm = lane & 15, quad = lane >> 4;

  const int sbid = xcd_swz(blockIdx.x, 1024);
  const int bm = sbid >> 3, bn = sbid & 7;
  const int row0 = bm * 64;   // token
  const int col0 = bn * 128;  // h2

  int e = 0, start = 0;
#pragma unroll
  for (int i = 0; i < E_N; i++) {
    int b = bsz[i];
    if (row0 >= start + b) { start += b; e = i + 1; }
  }
  const u16* mte = mt + (size_t)e * H_N * H_N;

  const int s_r = tid >> 2;      // 0..63
  const int s_k = (tid & 3) * 8;
  const u16* gA0 = xb + (size_t)(row0 + s_r) * H_N + s_k;
  const u16* gB0 = mte + (size_t)(col0 + s_r) * H_N + s_k;
  const u16* gB1 = gB0 + (size_t)64 * H_N;
  u16* ldsA_dst = ldsA + wv * 512;  // wave w stages A rows [16w,16w+16)
  u16* ldsB_dst = ldsB + wv * 512;

  f32x4 acc[2][4];
#pragma unroll
  for (int i = 0; i < 2; i++)
#pragma unroll
    for (int j = 0; j < 4; j++) acc[i][j] = (f32x4){0.f, 0.f, 0.f, 0.f};

  for (int k0 = 0; k0 < H_N; k0 += 32) {
    GLD2LDS16(gA0 + k0, ldsA_dst);
    GLD2LDS16(gB0 + k0, ldsB_dst);
    GLD2LDS16(gB1 + k0, ldsB_dst + 2048);

    __syncthreads();

    bf16x8 af[2], bfr[4];
#pragma unroll
    for (int mi = 0; mi < 2; mi++)
      af[mi] = *(const bf16x8*)(ldsA + (wm * 32 + mi * 16 + lm) * 32 + quad * 8);
#pragma unroll
    for (int ni = 0; ni < 4; ni++)
      bfr[ni] = *(const bf16x8*)(ldsB + (wn * 64 + ni * 16 + lm) * 32 + quad * 8);
#pragma unroll
    for (int mi = 0; mi < 2; mi++)
#pragma unroll
      for (int ni = 0; ni < 4; ni++)
        acc[mi][ni] = __builtin_amdgcn_mfma_f32_16x16x32_bf16(
            af[mi], bfr[ni], acc[mi][ni], 0, 0, 0);

    __syncthreads();
  }

  const int orow = row0 + wm * 32 + quad * 4;
  const int ocol = col0 + wn * 64 + lm;
#pragma unroll
  for (int mi = 0; mi < 2; mi++)
#pragma unroll
    for (int ni = 0; ni < 4; ni++)
#pragma unroll
      for (int r = 0; r < 4; r++)
        __builtin_nontemporal_store(
            acc[mi][ni][r],
            out + (size_t)(orow + mi * 16 + r) * H_N + ocol + ni * 16);
}

extern "C" void kernel_launch(void* const* d_in, const int* in_sizes, int n_in,
                              void* d_out, int out_size, void* d_ws,
                              size_t ws_size, hipStream_t stream) {
  (void)in_sizes; (void)n_in; (void)out_size;
  const float* hiddens = (const float*)d_in[0];
  const int* bsz = (const int*)d_in[1];
  const float* w1 = (const float*)d_in[2];
  const float* w2 = (const float*)d_in[3];
  float* out = (float*)d_out;

  // workspace layout (MiB): w1b 0:64 | w2t 64:128 | xb 128:144 | mt 144:160
  //                       | mtp (f32 split-K partials) 160:160+32*KSPLIT
  char* ws = (char*)d_ws;
  u16* w1b = (u16*)(ws);
  u16* w2t = (u16*)(ws + (size_t)64 * 1024 * 1024);
  u16* xb  = (u16*)(ws + (size_t)128 * 1024 * 1024);
  u16* mt  = (u16*)(ws + (size_t)144 * 1024 * 1024);
  float* mtp = (float*)(ws + (size_t)160 * 1024 * 1024);
  const size_t MiB = 1024 * 1024;
  const int ksplit = (ws_size >= 288 * MiB) ? 4 : (ws_size >= 224 * MiB ? 2 : 1);

  // fused pre-pass: bf16 conversions (+ W2 transpose), nt source loads
  prepass_kernel<<<dim3(NB_W1 + NB_X + NB_TR), 256, 0, stream>>>(
      w1, hiddens, w2, w1b, xb, w2t);

  // M^T per expert
  if (ksplit == 4) {
    wgemm_split_kernel<4><<<dim3(2048), 256, 0, stream>>>(w2t, w1b, mtp);
    reduce_mt_kernel<4><<<dim3(4096), 256, 0, stream>>>(mtp, mt);
  } else if (ksplit == 2) {
    wgemm_split_kernel<2><<<dim3(1024), 256, 0, stream>>>(w2t, w1b, mtp);
    reduce_mt_kernel<2><<<dim3(4096), 256, 0, stream>>>(mtp, mt);
  } else {
    wgemm_kernel<<<dim3(512), 256, 0, stream>>>(w2t, w1b, mt);
  }

  // down = x @ M  (64x128 tiles -> 1024 blocks = 4 blocks/CU)
  tgemm_kernel<<<dim3(1024), 256, 0, stream>>>(xb, bsz, mt, out);
}

// Round 4
// 410.065 us; speedup vs baseline: 1.2110x; 1.1295x over previous
//
#include <hip/hip_runtime.h>
#include <hip/hip_bf16.h>

// MoE experts, E=8 H=1024 I=4096 T=8192, f32 I/O, bf16 MFMA compute.
// Reassociation: M_e = W1_e @ W2_e (68.7 GF) then down = x @ M_e (17.2 GF).
// Round-6: wgemm ported to 256x256/BK=64, 8-wave, double-buffered LDS with
// counted vmcnt(8) (loads in flight across barriers, T3/T4), T2 XOR-swizzle
// (linear glds dest + pre-swizzled global source + swizzled ds_read),
// T5 setprio around MFMA. Round-3 counters: FETCH fixed (65 MB) but
// MfmaUtil 22% + 8.4M bank conflicts = 2-barrier structural ceiling.
// ksplit=2 (256 blocks = 1/CU; 64 MiB partials). tgemm/prepass unchanged.

typedef unsigned short u16;
typedef unsigned int u32;
typedef __attribute__((ext_vector_type(8))) short bf16x8;   // 8 bf16 = 4 VGPR
typedef __attribute__((ext_vector_type(4))) float f32x4;
typedef __attribute__((ext_vector_type(4))) u32 u32x4;

#define E_N 8
#define H_N 1024
#define I_N 4096
#define T_N 8192

// async global->LDS, 16B/lane; LDS dest is wave-uniform base + lane*16
#define GLD2LDS16(g, l)                                                        \
  __builtin_amdgcn_global_load_lds(                                            \
      (const __attribute__((address_space(1))) void*)(g),                      \
      (__attribute__((address_space(3))) void*)(l), 16, 0, 0)

// pack two f32 -> (lo,hi) bf16 pair, round-to-nearest (+0x8000, v_perm)
__device__ __forceinline__ u32 pkbf(float lo, float hi) {
  u32 a = __float_as_uint(lo) + 0x8000u;
  u32 b = __float_as_uint(hi) + 0x8000u;
  return __builtin_amdgcn_perm(b, a, 0x07060302u);
}

__device__ __forceinline__ u16 f2bf(float f) {
  __hip_bfloat16 h = __float2bfloat16(f);
  return *(reinterpret_cast<u16*>(&h));
}

// nontemporal 16B f32 load via ext-vector type (builtin rejects HIP float4)
__device__ __forceinline__ f32x4 ntload4(const float* p) {
  return __builtin_nontemporal_load((const f32x4*)p);
}

// T1: bijective chunked XCD swizzle (nwg % 8 == 0).
__device__ __forceinline__ int xcd_swz(int bid, int nwg) {
  const int chunk = nwg >> 3;
  return (bid & 7) * chunk + (bid >> 3);
}

// ---------------------------------------------------------------------------
// Fused pre-pass, one dispatch:
//   bid [0,16384)        : W1  f32 -> bf16      (w1b), nt loads
//   bid [16384,20480)    : x   f32 -> bf16      (xb),  nt loads
//   bid [20480,28672)    : W2  f32 -> bf16^T    (w2t), nt loads, LDS 64x65
// ---------------------------------------------------------------------------
#define NB_W1 16384
#define NB_X 4096
#define NB_TR 8192

__global__ __launch_bounds__(256) void prepass_kernel(
    const float* __restrict__ w1, const float* __restrict__ x,
    const float* __restrict__ w2, u16* __restrict__ w1b,
    u16* __restrict__ xb, u16* __restrict__ w2t) {
  __shared__ float tile[64 * 65];
  const int tid = threadIdx.x;
  const int bid = blockIdx.x;

  if (bid < NB_W1 + NB_X) {
    const float* src;
    u16* dst;
    size_t base;
    if (bid < NB_W1) {
      src = w1; dst = w1b; base = (size_t)bid * 2048;
    } else {
      src = x; dst = xb; base = (size_t)(bid - NB_W1) * 2048;
    }
    const size_t i = base + (size_t)tid * 8;
    f32x4 a = ntload4(src + i);
    f32x4 b = ntload4(src + i + 4);
    *(u32x4*)(dst + i) = (u32x4){pkbf(a.x, a.y), pkbf(a.z, a.w),
                                 pkbf(b.x, b.y), pkbf(b.z, b.w)};
    return;
  }

  // W2 [E][I][H] f32 -> W2T [E][H][I] bf16, 64x64 tiles (pad 65)
  const int b = bid - (NB_W1 + NB_X);
  const int e = b >> 10;
  const int rem = b & 1023;
  const int i0 = (rem >> 4) * 64;
  const int h0 = (rem & 15) * 64;
  const float* src = w2 + (size_t)e * I_N * H_N;
  u16* dst = w2t + (size_t)e * H_N * I_N;

  {
    const int r = tid >> 4;
    const int c4 = (tid & 15) * 4;
#pragma unroll
    for (int rr = 0; rr < 4; rr++) {
      const int row = rr * 16 + r;
      f32x4 v = ntload4(src + (size_t)(i0 + row) * H_N + h0 + c4);
      tile[row * 65 + c4 + 0] = v.x;
      tile[row * 65 + c4 + 1] = v.y;
      tile[row * 65 + c4 + 2] = v.z;
      tile[row * 65 + c4 + 3] = v.w;
    }
  }
  __syncthreads();

  {
    const int hr = tid >> 3;
    const int ic = (tid & 7) * 8;
#pragma unroll
    for (int hh = 0; hh < 2; hh++) {
      const int h = hh * 32 + hr;
      u32 p[4];
#pragma unroll
      for (int j = 0; j < 4; j++)
        p[j] = pkbf(tile[(ic + 2 * j) * 65 + h], tile[(ic + 2 * j + 1) * 65 + h]);
      *(u32x4*)(dst + (size_t)(h0 + h) * I_N + i0 + ic) =
          (u32x4){p[0], p[1], p[2], p[3]};
    }
  }
}

// ---------------------------------------------------------------------------
// Weight GEMM fallback (small-ws): 128x128, BK=32, 2-barrier structure.
// ---------------------------------------------------------------------------
__global__ __launch_bounds__(256) void wgemm_kernel(const u16* __restrict__ w2t,
                                                    const u16* __restrict__ w1b,
                                                    u16* __restrict__ mt) {
  __shared__ u16 ldsA[4096];
  __shared__ u16 ldsB[4096];

  const int tid = threadIdx.x;
  const int lane = tid & 63;
  const int wv = tid >> 6;
  const int wm = wv >> 1, wn = wv & 1;
  const int lm = lane & 15, quad = lane >> 4;

  const int sbid = xcd_swz(blockIdx.x, 512);
  const int e = sbid >> 6;
  const int t = sbid & 63;
  const int row0 = (t >> 3) * 128;
  const int col0 = (t & 7) * 128;

  const u16* Ae = w2t + (size_t)e * H_N * I_N;
  const u16* Be = w1b + (size_t)e * H_N * I_N;
  u16* mte = mt + (size_t)e * H_N * H_N;

  const int s_r = tid >> 2;
  const int s_k = (tid & 3) * 8;
  const u16* gA0 = Ae + (size_t)(row0 + s_r) * I_N + s_k;
  const u16* gA1 = gA0 + (size_t)64 * I_N;
  const u16* gB0 = Be + (size_t)(col0 + s_r) * I_N + s_k;
  const u16* gB1 = gB0 + (size_t)64 * I_N;
  u16* ldsA_dst = ldsA + wv * 512;
  u16* ldsB_dst = ldsB + wv * 512;

  f32x4 acc[4][4];
#pragma unroll
  for (int i = 0; i < 4; i++)
#pragma unroll
    for (int j = 0; j < 4; j++) acc[i][j] = (f32x4){0.f, 0.f, 0.f, 0.f};

  for (int k0 = 0; k0 < I_N; k0 += 32) {
    GLD2LDS16(gA0 + k0, ldsA_dst);
    GLD2LDS16(gA1 + k0, ldsA_dst + 2048);
    GLD2LDS16(gB0 + k0, ldsB_dst);
    GLD2LDS16(gB1 + k0, ldsB_dst + 2048);

    __syncthreads();

    bf16x8 af[4], bfr[4];
#pragma unroll
    for (int mi = 0; mi < 4; mi++)
      af[mi] = *(const bf16x8*)(ldsA + (wm * 64 + mi * 16 + lm) * 32 + quad * 8);
#pragma unroll
    for (int ni = 0; ni < 4; ni++)
      bfr[ni] = *(const bf16x8*)(ldsB + (wn * 64 + ni * 16 + lm) * 32 + quad * 8);
#pragma unroll
    for (int mi = 0; mi < 4; mi++)
#pragma unroll
      for (int ni = 0; ni < 4; ni++)
        acc[mi][ni] = __builtin_amdgcn_mfma_f32_16x16x32_bf16(
            af[mi], bfr[ni], acc[mi][ni], 0, 0, 0);

    __syncthreads();
  }

  const int orow = row0 + wm * 64 + quad * 4;
  const int ocol = col0 + wn * 64 + lm;
#pragma unroll
  for (int mi = 0; mi < 4; mi++)
#pragma unroll
    for (int ni = 0; ni < 4; ni++)
#pragma unroll
      for (int r = 0; r < 4; r++)
        mte[(size_t)(orow + mi * 16 + r) * H_N + ocol + ni * 16] =
            f2bf(acc[mi][ni][r]);
}

// ---------------------------------------------------------------------------
// Weight GEMM, deep-pipelined: 256x256 tile, BK=64, 8 waves (2M x 4N),
// double-buffered 128 KiB LDS, counted vmcnt(8), T2 XOR-swizzle, split-K x2.
// Block: kh(2) x e(8) x tile(16).  Grid 256 = 1 block/CU.
// LDS layout (u16): A0[0,16K) B0[16K,32K) A1[32K,48K) B1[48K,64K);
// each tile row-major [256][64] bf16 (128 B/row), data at column
// colbyte ^ ((row&7)<<4)  (involution; applied on source AND read).
// ---------------------------------------------------------------------------
__global__ __launch_bounds__(512, 2) void wgemm8_kernel(
    const u16* __restrict__ w2t, const u16* __restrict__ w1b,
    float* __restrict__ mtp) {
  __shared__ u16 lds[65536];  // 128 KiB

  const int tid = threadIdx.x;
  const int lane = tid & 63;
  const int wv = tid >> 6;           // 0..7
  const int wm = wv >> 2;            // 0..1  (M halves of 128)
  const int wn = wv & 3;             // 0..3  (N quarters of 64)
  const int lm = lane & 15, quad = lane >> 4;

  const int sbid = xcd_swz(blockIdx.x, 256);
  const int kh = sbid >> 7;          // split-K half
  const int rem = sbid & 127;
  const int e = rem >> 4;
  const int t = rem & 15;
  const int row0 = (t >> 2) * 256;   // h2 (A rows)
  const int col0 = (t & 3) * 256;    // h1 (B rows)

  const u16* Ae = w2t + (size_t)e * H_N * I_N;
  const u16* Be = w1b + (size_t)e * H_N * I_N;

  // staging: thread covers LDS rows {j*64 + tid>>3}, 16 B at colbyte
  // (tid&7)*16. Pre-swizzle the SOURCE column so swizzled-read sees
  // linear data: src col elems = ((tid&7) ^ ((tid>>3)&7)) * 8.
  const int srow = tid >> 3;                       // 0..63
  const int koff = ((tid & 7) ^ (srow & 7)) * 8;   // 0..56
  const u16* gA = Ae + (size_t)(row0 + srow) * I_N + koff;
  const u16* gB = Be + (size_t)(col0 + srow) * I_N + koff;
  u16* stA = lds + wv * 512;                        // + bsel*32768 + j*4096
  u16* stB = stA + 16384;

  // ds_read column offsets (u16 units), swizzled, per k-half
  const int sw = (lm & 7) << 4;                       // bytes
  const int c0 = (((quad << 4)) ^ sw) >> 1;           // k-half 0
  const int c1 = ((64 | (quad << 4)) ^ sw) >> 1;      // k-half 1
  const int rdA = (wm * 128 + lm) * 64;               // + mi*1024
  const int rdB = (wn * 64 + lm) * 64;                // + ni*1024

  f32x4 acc[8][4];
#pragma unroll
  for (int i = 0; i < 8; i++)
#pragma unroll
    for (int j = 0; j < 4; j++) acc[i][j] = (f32x4){0.f, 0.f, 0.f, 0.f};

  const int kbeg = kh * (I_N / 2);
  const int NT = (I_N / 2) / 64;     // 32 K-tiles

#define STAGE8(bsel, k0)                                                       \
  do {                                                                         \
    u16* la = stA + (bsel)*32768;                                              \
    u16* lb = stB + (bsel)*32768;                                              \
    const u16* ga = gA + (k0);                                                 \
    const u16* gb = gB + (k0);                                                 \
    GLD2LDS16(ga, la);                                                         \
    GLD2LDS16(ga + (size_t)64 * I_N, la + 4096);                               \
    GLD2LDS16(ga + (size_t)128 * I_N, la + 8192);                              \
    GLD2LDS16(ga + (size_t)192 * I_N, la + 12288);                             \
    GLD2LDS16(gb, lb);                                                         \
    GLD2LDS16(gb + (size_t)64 * I_N, lb + 4096);                               \
    GLD2LDS16(gb + (size_t)128 * I_N, lb + 8192);                              \
    GLD2LDS16(gb + (size_t)192 * I_N, lb + 12288);                             \
  } while (0)

  STAGE8(0, kbeg);
  for (int kt = 0; kt < NT; ++kt) {
    // stage next tile, then wait ONLY for the current tile's 8 loads
    // (next tile's 8 stay in flight across the barrier -> T4)
    if (kt + 1 < NT) {
      STAGE8((kt + 1) & 1, kbeg + (kt + 1) * 64);
      asm volatile("s_waitcnt vmcnt(8)" ::: "memory");
    } else {
      asm volatile("s_waitcnt vmcnt(0)" ::: "memory");
    }
    asm volatile("s_barrier" ::: "memory");  // tile kt complete block-wide

    const u16* bufA = lds + (kt & 1) * 32768;
    const u16* bufB = bufA + 16384;
#pragma unroll
    for (int kh2 = 0; kh2 < 2; ++kh2) {
      const int cc = kh2 ? c1 : c0;
      bf16x8 a[8], b[4];
#pragma unroll
      for (int ni = 0; ni < 4; ni++)
        b[ni] = *(const bf16x8*)(bufB + rdB + ni * 1024 + cc);
#pragma unroll
      for (int mi = 0; mi < 8; mi++)
        a[mi] = *(const bf16x8*)(bufA + rdA + mi * 1024 + cc);
      __builtin_amdgcn_s_setprio(1);
#pragma unroll
      for (int mi = 0; mi < 8; mi++)
#pragma unroll
        for (int ni = 0; ni < 4; ni++)
          acc[mi][ni] = __builtin_amdgcn_mfma_f32_16x16x32_bf16(
              a[mi], b[ni], acc[mi][ni], 0, 0, 0);
      __builtin_amdgcn_s_setprio(0);
    }
    // all waves done reading buf[kt&1]; next iter may overwrite it
    asm volatile("s_barrier" ::: "memory");
  }
#undef STAGE8

  // f32 partials (nt: read exactly once by reduce)
  float* dst = mtp + (size_t)(kh * E_N + e) * H_N * H_N;
  const int orow = row0 + wm * 128 + quad * 4;
  const int ocol = col0 + wn * 64 + lm;
#pragma unroll
  for (int mi = 0; mi < 8; mi++)
#pragma unroll
    for (int ni = 0; ni < 4; ni++)
#pragma unroll
      for (int r = 0; r < 4; r++)
        __builtin_nontemporal_store(
            acc[mi][ni][r],
            dst + (size_t)(orow + mi * 16 + r) * H_N + ocol + ni * 16);
}

// ---------------------------------------------------------------------------
// mt[i] = bf16(sum_p mtp[p][i]); 8 elems/thread, nt loads.
// ---------------------------------------------------------------------------
template <int KSPLIT>
__global__ __launch_bounds__(256) void reduce_mt_kernel(
    const float* __restrict__ mtp, u16* __restrict__ mt) {
  const size_t i = ((size_t)blockIdx.x * 256 + threadIdx.x) * 8;
  float s[8];
#pragma unroll
  for (int j = 0; j < 8; j++) s[j] = 0.f;
#pragma unroll
  for (int p = 0; p < KSPLIT; p++) {
    const float* q = mtp + (size_t)p * E_N * H_N * H_N + i;
    f32x4 a = ntload4(q);
    f32x4 b = ntload4(q + 4);
    s[0] += a.x; s[1] += a.y; s[2] += a.z; s[3] += a.w;
    s[4] += b.x; s[5] += b.y; s[6] += b.z; s[7] += b.w;
  }
  *(u32x4*)(mt + i) = (u32x4){pkbf(s[0], s[1]), pkbf(s[2], s[3]),
                              pkbf(s[4], s[5]), pkbf(s[6], s[7])};
}

// ---------------------------------------------------------------------------
// Token GEMM: out[t][h2] = sum_h1 xb[t][h1] * Mt[e(t)][h2][h1]
// 64x128 tile (1024 blocks, T1 swizzle), BK=32, 2x2 waves of 32x64.
// ---------------------------------------------------------------------------
__global__ __launch_bounds__(256) void tgemm_kernel(const u16* __restrict__ xb,
                                                    const int* __restrict__ bsz,
                                                    const u16* __restrict__ mt,
                                                    float* __restrict__ out) {
  __shared__ u16 ldsA[2048];
  __shared__ u16 ldsB[4096];

  const int tid = threadIdx.x;
  const int lane = tid & 63;
  const int wv = tid >> 6;
  const int wm = wv >> 1, wn = wv & 1;
  const int lm = lane & 15, quad = lane >> 4;

  const int sbid = xcd_swz(blockIdx.x, 1024);
  const int bm = sbid >> 3, bn = sbid & 7;
  const int row0 = bm * 64;
  const int col0 = bn * 128;

  int e = 0, start = 0;
#pragma unroll
  for (int i = 0; i < E_N; i++) {
    int b = bsz[i];
    if (row0 >= start + b) { start += b; e = i + 1; }
  }
  const u16* mte = mt + (size_t)e * H_N * H_N;

  const int s_r = tid >> 2;
  const int s_k = (tid & 3) * 8;
  const u16* gA0 = xb + (size_t)(row0 + s_r) * H_N + s_k;
  const u16* gB0 = mte + (size_t)(col0 + s_r) * H_N + s_k;
  const u16* gB1 = gB0 + (size_t)64 * H_N;
  u16* ldsA_dst = ldsA + wv * 512;
  u16* ldsB_dst = ldsB + wv * 512;

  f32x4 acc[2][4];
#pragma unroll
  for (int i = 0; i < 2; i++)
#pragma unroll
    for (int j = 0; j < 4; j++) acc[i][j] = (f32x4){0.f, 0.f, 0.f, 0.f};

  for (int k0 = 0; k0 < H_N; k0 += 32) {
    GLD2LDS16(gA0 + k0, ldsA_dst);
    GLD2LDS16(gB0 + k0, ldsB_dst);
    GLD2LDS16(gB1 + k0, ldsB_dst + 2048);

    __syncthreads();

    bf16x8 af[2], bfr[4];
#pragma unroll
    for (int mi = 0; mi < 2; mi++)
      af[mi] = *(const bf16x8*)(ldsA + (wm * 32 + mi * 16 + lm) * 32 + quad * 8);
#pragma unroll
    for (int ni = 0; ni < 4; ni++)
      bfr[ni] = *(const bf16x8*)(ldsB + (wn * 64 + ni * 16 + lm) * 32 + quad * 8);
#pragma unroll
    for (int mi = 0; mi < 2; mi++)
#pragma unroll
      for (int ni = 0; ni < 4; ni++)
        acc[mi][ni] = __builtin_amdgcn_mfma_f32_16x16x32_bf16(
            af[mi], bfr[ni], acc[mi][ni], 0, 0, 0);

    __syncthreads();
  }

  const int orow = row0 + wm * 32 + quad * 4;
  const int ocol = col0 + wn * 64 + lm;
#pragma unroll
  for (int mi = 0; mi < 2; mi++)
#pragma unroll
    for (int ni = 0; ni < 4; ni++)
#pragma unroll
      for (int r = 0; r < 4; r++)
        __builtin_nontemporal_store(
            acc[mi][ni][r],
            out + (size_t)(orow + mi * 16 + r) * H_N + ocol + ni * 16);
}

extern "C" void kernel_launch(void* const* d_in, const int* in_sizes, int n_in,
                              void* d_out, int out_size, void* d_ws,
                              size_t ws_size, hipStream_t stream) {
  (void)in_sizes; (void)n_in; (void)out_size;
  const float* hiddens = (const float*)d_in[0];
  const int* bsz = (const int*)d_in[1];
  const float* w1 = (const float*)d_in[2];
  const float* w2 = (const float*)d_in[3];
  float* out = (float*)d_out;

  // workspace layout (MiB): w1b 0:64 | w2t 64:128 | xb 128:144 | mt 144:160
  //                       | mtp (f32 split-K partials, x2) 160:224
  char* ws = (char*)d_ws;
  u16* w1b = (u16*)(ws);
  u16* w2t = (u16*)(ws + (size_t)64 * 1024 * 1024);
  u16* xb  = (u16*)(ws + (size_t)128 * 1024 * 1024);
  u16* mt  = (u16*)(ws + (size_t)144 * 1024 * 1024);
  float* mtp = (float*)(ws + (size_t)160 * 1024 * 1024);
  const size_t MiB = 1024 * 1024;

  // fused pre-pass: bf16 conversions (+ W2 transpose), nt source loads
  prepass_kernel<<<dim3(NB_W1 + NB_X + NB_TR), 256, 0, stream>>>(
      w1, hiddens, w2, w1b, xb, w2t);

  // M^T per expert
  if (ws_size >= 224 * MiB) {
    wgemm8_kernel<<<dim3(256), 512, 0, stream>>>(w2t, w1b, mtp);
    reduce_mt_kernel<2><<<dim3(4096), 256, 0, stream>>>(mtp, mt);
  } else {
    wgemm_kernel<<<dim3(512), 256, 0, stream>>>(w2t, w1b, mt);
  }

  // down = x @ M  (64x128 tiles -> 1024 blocks = 4 blocks/CU)
  tgemm_kernel<<<dim3(1024), 256, 0, stream>>>(xb, bsz, mt, out);
}

// Round 5
// 404.620 us; speedup vs baseline: 1.2273x; 1.0135x over previous
//
#include <hip/hip_runtime.h>
#include <hip/hip_bf16.h>

// MoE experts, E=8 H=1024 I=4096 T=8192, f32 I/O, bf16 MFMA compute.
// Reassociation: M_e = W1_e @ W2_e (68.7 GF) then down = x @ M_e (17.2 GF).
// Round-7: port tgemm to the HW-proven wgemm8 structure (counted vmcnt(6),
// both-sides XOR swizzle, raw barrier pairs, 128x256/BK=64, 8 waves).
// Round-4 counters: wgemm8 833 TF, 0 bank conflicts, MfmaUtil 33% --
// schedule-limited (1-phase counted). tgemm was still the old 2-barrier
// vmcnt(0) + 16-way-conflict structure. XCD chunk = 32 blocks = exactly one
// expert -> mt panel (2 MiB) L2-resident per XCD. wgemm8/prepass/reduce
// untouched.

typedef unsigned short u16;
typedef unsigned int u32;
typedef __attribute__((ext_vector_type(8))) short bf16x8;   // 8 bf16 = 4 VGPR
typedef __attribute__((ext_vector_type(4))) float f32x4;
typedef __attribute__((ext_vector_type(4))) u32 u32x4;

#define E_N 8
#define H_N 1024
#define I_N 4096
#define T_N 8192

// async global->LDS, 16B/lane; LDS dest is wave-uniform base + lane*16
#define GLD2LDS16(g, l)                                                        \
  __builtin_amdgcn_global_load_lds(                                            \
      (const __attribute__((address_space(1))) void*)(g),                      \
      (__attribute__((address_space(3))) void*)(l), 16, 0, 0)

// pack two f32 -> (lo,hi) bf16 pair, round-to-nearest (+0x8000, v_perm)
__device__ __forceinline__ u32 pkbf(float lo, float hi) {
  u32 a = __float_as_uint(lo) + 0x8000u;
  u32 b = __float_as_uint(hi) + 0x8000u;
  return __builtin_amdgcn_perm(b, a, 0x07060302u);
}

__device__ __forceinline__ u16 f2bf(float f) {
  __hip_bfloat16 h = __float2bfloat16(f);
  return *(reinterpret_cast<u16*>(&h));
}

// nontemporal 16B f32 load via ext-vector type (builtin rejects HIP float4)
__device__ __forceinline__ f32x4 ntload4(const float* p) {
  return __builtin_nontemporal_load((const f32x4*)p);
}

// T1: bijective chunked XCD swizzle (nwg % 8 == 0).
__device__ __forceinline__ int xcd_swz(int bid, int nwg) {
  const int chunk = nwg >> 3;
  return (bid & 7) * chunk + (bid >> 3);
}

// ---------------------------------------------------------------------------
// Fused pre-pass, one dispatch:
//   bid [0,16384)        : W1  f32 -> bf16      (w1b), nt loads
//   bid [16384,20480)    : x   f32 -> bf16      (xb),  nt loads
//   bid [20480,28672)    : W2  f32 -> bf16^T    (w2t), nt loads, LDS 64x65
// ---------------------------------------------------------------------------
#define NB_W1 16384
#define NB_X 4096
#define NB_TR 8192

__global__ __launch_bounds__(256) void prepass_kernel(
    const float* __restrict__ w1, const float* __restrict__ x,
    const float* __restrict__ w2, u16* __restrict__ w1b,
    u16* __restrict__ xb, u16* __restrict__ w2t) {
  __shared__ float tile[64 * 65];
  const int tid = threadIdx.x;
  const int bid = blockIdx.x;

  if (bid < NB_W1 + NB_X) {
    const float* src;
    u16* dst;
    size_t base;
    if (bid < NB_W1) {
      src = w1; dst = w1b; base = (size_t)bid * 2048;
    } else {
      src = x; dst = xb; base = (size_t)(bid - NB_W1) * 2048;
    }
    const size_t i = base + (size_t)tid * 8;
    f32x4 a = ntload4(src + i);
    f32x4 b = ntload4(src + i + 4);
    *(u32x4*)(dst + i) = (u32x4){pkbf(a.x, a.y), pkbf(a.z, a.w),
                                 pkbf(b.x, b.y), pkbf(b.z, b.w)};
    return;
  }

  // W2 [E][I][H] f32 -> W2T [E][H][I] bf16, 64x64 tiles (pad 65)
  const int b = bid - (NB_W1 + NB_X);
  const int e = b >> 10;
  const int rem = b & 1023;
  const int i0 = (rem >> 4) * 64;
  const int h0 = (rem & 15) * 64;
  const float* src = w2 + (size_t)e * I_N * H_N;
  u16* dst = w2t + (size_t)e * H_N * I_N;

  {
    const int r = tid >> 4;
    const int c4 = (tid & 15) * 4;
#pragma unroll
    for (int rr = 0; rr < 4; rr++) {
      const int row = rr * 16 + r;
      f32x4 v = ntload4(src + (size_t)(i0 + row) * H_N + h0 + c4);
      tile[row * 65 + c4 + 0] = v.x;
      tile[row * 65 + c4 + 1] = v.y;
      tile[row * 65 + c4 + 2] = v.z;
      tile[row * 65 + c4 + 3] = v.w;
    }
  }
  __syncthreads();

  {
    const int hr = tid >> 3;
    const int ic = (tid & 7) * 8;
#pragma unroll
    for (int hh = 0; hh < 2; hh++) {
      const int h = hh * 32 + hr;
      u32 p[4];
#pragma unroll
      for (int j = 0; j < 4; j++)
        p[j] = pkbf(tile[(ic + 2 * j) * 65 + h], tile[(ic + 2 * j + 1) * 65 + h]);
      *(u32x4*)(dst + (size_t)(h0 + h) * I_N + i0 + ic) =
          (u32x4){p[0], p[1], p[2], p[3]};
    }
  }
}

// ---------------------------------------------------------------------------
// Weight GEMM fallback (small-ws): 128x128, BK=32, 2-barrier structure.
// ---------------------------------------------------------------------------
__global__ __launch_bounds__(256) void wgemm_kernel(const u16* __restrict__ w2t,
                                                    const u16* __restrict__ w1b,
                                                    u16* __restrict__ mt) {
  __shared__ u16 ldsA[4096];
  __shared__ u16 ldsB[4096];

  const int tid = threadIdx.x;
  const int lane = tid & 63;
  const int wv = tid >> 6;
  const int wm = wv >> 1, wn = wv & 1;
  const int lm = lane & 15, quad = lane >> 4;

  const int sbid = xcd_swz(blockIdx.x, 512);
  const int e = sbid >> 6;
  const int t = sbid & 63;
  const int row0 = (t >> 3) * 128;
  const int col0 = (t & 7) * 128;

  const u16* Ae = w2t + (size_t)e * H_N * I_N;
  const u16* Be = w1b + (size_t)e * H_N * I_N;
  u16* mte = mt + (size_t)e * H_N * H_N;

  const int s_r = tid >> 2;
  const int s_k = (tid & 3) * 8;
  const u16* gA0 = Ae + (size_t)(row0 + s_r) * I_N + s_k;
  const u16* gA1 = gA0 + (size_t)64 * I_N;
  const u16* gB0 = Be + (size_t)(col0 + s_r) * I_N + s_k;
  const u16* gB1 = gB0 + (size_t)64 * I_N;
  u16* ldsA_dst = ldsA + wv * 512;
  u16* ldsB_dst = ldsB + wv * 512;

  f32x4 acc[4][4];
#pragma unroll
  for (int i = 0; i < 4; i++)
#pragma unroll
    for (int j = 0; j < 4; j++) acc[i][j] = (f32x4){0.f, 0.f, 0.f, 0.f};

  for (int k0 = 0; k0 < I_N; k0 += 32) {
    GLD2LDS16(gA0 + k0, ldsA_dst);
    GLD2LDS16(gA1 + k0, ldsA_dst + 2048);
    GLD2LDS16(gB0 + k0, ldsB_dst);
    GLD2LDS16(gB1 + k0, ldsB_dst + 2048);

    __syncthreads();

    bf16x8 af[4], bfr[4];
#pragma unroll
    for (int mi = 0; mi < 4; mi++)
      af[mi] = *(const bf16x8*)(ldsA + (wm * 64 + mi * 16 + lm) * 32 + quad * 8);
#pragma unroll
    for (int ni = 0; ni < 4; ni++)
      bfr[ni] = *(const bf16x8*)(ldsB + (wn * 64 + ni * 16 + lm) * 32 + quad * 8);
#pragma unroll
    for (int mi = 0; mi < 4; mi++)
#pragma unroll
      for (int ni = 0; ni < 4; ni++)
        acc[mi][ni] = __builtin_amdgcn_mfma_f32_16x16x32_bf16(
            af[mi], bfr[ni], acc[mi][ni], 0, 0, 0);

    __syncthreads();
  }

  const int orow = row0 + wm * 64 + quad * 4;
  const int ocol = col0 + wn * 64 + lm;
#pragma unroll
  for (int mi = 0; mi < 4; mi++)
#pragma unroll
    for (int ni = 0; ni < 4; ni++)
#pragma unroll
      for (int r = 0; r < 4; r++)
        mte[(size_t)(orow + mi * 16 + r) * H_N + ocol + ni * 16] =
            f2bf(acc[mi][ni][r]);
}

// ---------------------------------------------------------------------------
// Weight GEMM, deep-pipelined: 256x256 tile, BK=64, 8 waves (2M x 4N),
// double-buffered 128 KiB LDS, counted vmcnt(8), T2 XOR-swizzle, split-K x2.
// Grid 256 = 1 block/CU.  (HW-verified round 4: 833 TF, 0 bank conflicts.)
// ---------------------------------------------------------------------------
__global__ __launch_bounds__(512, 2) void wgemm8_kernel(
    const u16* __restrict__ w2t, const u16* __restrict__ w1b,
    float* __restrict__ mtp) {
  __shared__ u16 lds[65536];  // 128 KiB

  const int tid = threadIdx.x;
  const int lane = tid & 63;
  const int wv = tid >> 6;           // 0..7
  const int wm = wv >> 2;            // 0..1  (M halves of 128)
  const int wn = wv & 3;             // 0..3  (N quarters of 64)
  const int lm = lane & 15, quad = lane >> 4;

  const int sbid = xcd_swz(blockIdx.x, 256);
  const int kh = sbid >> 7;          // split-K half
  const int rem = sbid & 127;
  const int e = rem >> 4;
  const int t = rem & 15;
  const int row0 = (t >> 2) * 256;   // h2 (A rows)
  const int col0 = (t & 3) * 256;    // h1 (B rows)

  const u16* Ae = w2t + (size_t)e * H_N * I_N;
  const u16* Be = w1b + (size_t)e * H_N * I_N;

  const int srow = tid >> 3;                       // 0..63
  const int koff = ((tid & 7) ^ (srow & 7)) * 8;   // pre-swizzled source col
  const u16* gA = Ae + (size_t)(row0 + srow) * I_N + koff;
  const u16* gB = Be + (size_t)(col0 + srow) * I_N + koff;
  u16* stA = lds + wv * 512;                        // + bsel*32768 + j*4096
  u16* stB = stA + 16384;

  const int sw = (lm & 7) << 4;                       // bytes
  const int c0 = (((quad << 4)) ^ sw) >> 1;           // k-half 0
  const int c1 = ((64 | (quad << 4)) ^ sw) >> 1;      // k-half 1
  const int rdA = (wm * 128 + lm) * 64;               // + mi*1024
  const int rdB = (wn * 64 + lm) * 64;                // + ni*1024

  f32x4 acc[8][4];
#pragma unroll
  for (int i = 0; i < 8; i++)
#pragma unroll
    for (int j = 0; j < 4; j++) acc[i][j] = (f32x4){0.f, 0.f, 0.f, 0.f};

  const int kbeg = kh * (I_N / 2);
  const int NT = (I_N / 2) / 64;     // 32 K-tiles

#define STAGE8(bsel, k0)                                                       \
  do {                                                                         \
    u16* la = stA + (bsel)*32768;                                              \
    u16* lb = stB + (bsel)*32768;                                              \
    const u16* ga = gA + (k0);                                                 \
    const u16* gb = gB + (k0);                                                 \
    GLD2LDS16(ga, la);                                                         \
    GLD2LDS16(ga + (size_t)64 * I_N, la + 4096);                               \
    GLD2LDS16(ga + (size_t)128 * I_N, la + 8192);                              \
    GLD2LDS16(ga + (size_t)192 * I_N, la + 12288);                             \
    GLD2LDS16(gb, lb);                                                         \
    GLD2LDS16(gb + (size_t)64 * I_N, lb + 4096);                               \
    GLD2LDS16(gb + (size_t)128 * I_N, lb + 8192);                              \
    GLD2LDS16(gb + (size_t)192 * I_N, lb + 12288);                             \
  } while (0)

  STAGE8(0, kbeg);
  for (int kt = 0; kt < NT; ++kt) {
    if (kt + 1 < NT) {
      STAGE8((kt + 1) & 1, kbeg + (kt + 1) * 64);
      asm volatile("s_waitcnt vmcnt(8)" ::: "memory");
    } else {
      asm volatile("s_waitcnt vmcnt(0)" ::: "memory");
    }
    asm volatile("s_barrier" ::: "memory");

    const u16* bufA = lds + (kt & 1) * 32768;
    const u16* bufB = bufA + 16384;
#pragma unroll
    for (int kh2 = 0; kh2 < 2; ++kh2) {
      const int cc = kh2 ? c1 : c0;
      bf16x8 a[8], b[4];
#pragma unroll
      for (int ni = 0; ni < 4; ni++)
        b[ni] = *(const bf16x8*)(bufB + rdB + ni * 1024 + cc);
#pragma unroll
      for (int mi = 0; mi < 8; mi++)
        a[mi] = *(const bf16x8*)(bufA + rdA + mi * 1024 + cc);
      __builtin_amdgcn_s_setprio(1);
#pragma unroll
      for (int mi = 0; mi < 8; mi++)
#pragma unroll
        for (int ni = 0; ni < 4; ni++)
          acc[mi][ni] = __builtin_amdgcn_mfma_f32_16x16x32_bf16(
              a[mi], b[ni], acc[mi][ni], 0, 0, 0);
      __builtin_amdgcn_s_setprio(0);
    }
    asm volatile("s_barrier" ::: "memory");
  }
#undef STAGE8

  float* dst = mtp + (size_t)(kh * E_N + e) * H_N * H_N;
  const int orow = row0 + wm * 128 + quad * 4;
  const int ocol = col0 + wn * 64 + lm;
#pragma unroll
  for (int mi = 0; mi < 8; mi++)
#pragma unroll
    for (int ni = 0; ni < 4; ni++)
#pragma unroll
      for (int r = 0; r < 4; r++)
        __builtin_nontemporal_store(
            acc[mi][ni][r],
            dst + (size_t)(orow + mi * 16 + r) * H_N + ocol + ni * 16);
}

// ---------------------------------------------------------------------------
// mt[i] = bf16(sum_p mtp[p][i]); 8 elems/thread, nt loads.
// ---------------------------------------------------------------------------
template <int KSPLIT>
__global__ __launch_bounds__(256) void reduce_mt_kernel(
    const float* __restrict__ mtp, u16* __restrict__ mt) {
  const size_t i = ((size_t)blockIdx.x * 256 + threadIdx.x) * 8;
  float s[8];
#pragma unroll
  for (int j = 0; j < 8; j++) s[j] = 0.f;
#pragma unroll
  for (int p = 0; p < KSPLIT; p++) {
    const float* q = mtp + (size_t)p * E_N * H_N * H_N + i;
    f32x4 a = ntload4(q);
    f32x4 b = ntload4(q + 4);
    s[0] += a.x; s[1] += a.y; s[2] += a.z; s[3] += a.w;
    s[4] += b.x; s[5] += b.y; s[6] += b.z; s[7] += b.w;
  }
  *(u32x4*)(mt + i) = (u32x4){pkbf(s[0], s[1]), pkbf(s[2], s[3]),
                              pkbf(s[4], s[5]), pkbf(s[6], s[7])};
}

// ---------------------------------------------------------------------------
// Token GEMM, deep-pipelined (wgemm8 structure): out[t][h2] =
// sum_h1 xb[t][h1] * Mt[e(t)][h2][h1].  128x256 tile, BK=64, 8 waves
// (2M x 4N, wave 64x64), 96 KiB dbuf LDS, counted vmcnt(6), both-sides
// XOR swizzle.  Grid 256 = 1/CU; XCD chunk (32 blocks) == one expert ->
// mt panel (2 MiB) stays in that XCD's L2.  Output f32 nt.
// LDS buffer d at d*24576 (u16): A [128][64] at +0, B [256][64] at +8192.
// ---------------------------------------------------------------------------
__global__ __launch_bounds__(512, 2) void tgemm8_kernel(
    const u16* __restrict__ xb, const int* __restrict__ bsz,
    const u16* __restrict__ mt, float* __restrict__ out) {
  __shared__ u16 lds[49152];  // 96 KiB

  const int tid = threadIdx.x;
  const int lane = tid & 63;
  const int wv = tid >> 6;           // 0..7
  const int wm = wv >> 2;            // 0..1  (token halves of 64)
  const int wn = wv & 3;             // 0..3  (h2 quarters of 64)
  const int lm = lane & 15, quad = lane >> 4;

  const int sbid = xcd_swz(blockIdx.x, 256);
  const int bm = sbid >> 2;          // 0..63 token tile
  const int bn = sbid & 3;           // 0..3  h2 tile
  const int row0 = bm * 128;         // token
  const int col0 = bn * 256;         // h2

  int e = 0, start = 0;
#pragma unroll
  for (int i = 0; i < E_N; i++) {
    int b = bsz[i];
    if (row0 >= start + b) { start += b; e = i + 1; }
  }
  const u16* mte = mt + (size_t)e * H_N * H_N;

  const int srow = tid >> 3;                       // 0..63
  const int koff = ((tid & 7) ^ (srow & 7)) * 8;   // pre-swizzled source col
  const u16* gA = xb + (size_t)(row0 + srow) * H_N + koff;
  const u16* gB = mte + (size_t)(col0 + srow) * H_N + koff;
  u16* stA = lds + wv * 512;          // + bsel*24576 (+ pass*4096)
  u16* stB = stA + 8192;

  const int sw = (lm & 7) << 4;
  const int c0 = (((quad << 4)) ^ sw) >> 1;
  const int c1 = ((64 | (quad << 4)) ^ sw) >> 1;
  const int rdA = (wm * 64 + lm) * 64;   // + mi*1024
  const int rdB = (wn * 64 + lm) * 64;   // + ni*1024

  f32x4 acc[4][4];
#pragma unroll
  for (int i = 0; i < 4; i++)
#pragma unroll
    for (int j = 0; j < 4; j++) acc[i][j] = (f32x4){0.f, 0.f, 0.f, 0.f};

  const int NT = H_N / 64;           // 16 K-tiles

#define TSTAGE6(bsel, k0)                                                      \
  do {                                                                         \
    u16* la = stA + (bsel)*24576;                                              \
    u16* lb = stB + (bsel)*24576;                                              \
    const u16* ga = gA + (k0);                                                 \
    const u16* gb = gB + (k0);                                                 \
    GLD2LDS16(ga, la);                                                         \
    GLD2LDS16(ga + (size_t)64 * H_N, la + 4096);                               \
    GLD2LDS16(gb, lb);                                                         \
    GLD2LDS16(gb + (size_t)64 * H_N, lb + 4096);                               \
    GLD2LDS16(gb + (size_t)128 * H_N, lb + 8192);                              \
    GLD2LDS16(gb + (size_t)192 * H_N, lb + 12288);                             \
  } while (0)

  TSTAGE6(0, 0);
  for (int kt = 0; kt < NT; ++kt) {
    if (kt + 1 < NT) {
      TSTAGE6((kt + 1) & 1, (kt + 1) * 64);
      asm volatile("s_waitcnt vmcnt(6)" ::: "memory");
    } else {
      asm volatile("s_waitcnt vmcnt(0)" ::: "memory");
    }
    asm volatile("s_barrier" ::: "memory");

    const u16* bufA = lds + (kt & 1) * 24576;
    const u16* bufB = bufA + 8192;
#pragma unroll
    for (int kh2 = 0; kh2 < 2; ++kh2) {
      const int cc = kh2 ? c1 : c0;
      bf16x8 a[4], b[4];
#pragma unroll
      for (int ni = 0; ni < 4; ni++)
        b[ni] = *(const bf16x8*)(bufB + rdB + ni * 1024 + cc);
#pragma unroll
      for (int mi = 0; mi < 4; mi++)
        a[mi] = *(const bf16x8*)(bufA + rdA + mi * 1024 + cc);
      __builtin_amdgcn_s_setprio(1);
#pragma unroll
      for (int mi = 0; mi < 4; mi++)
#pragma unroll
        for (int ni = 0; ni < 4; ni++)
          acc[mi][ni] = __builtin_amdgcn_mfma_f32_16x16x32_bf16(
              a[mi], b[ni], acc[mi][ni], 0, 0, 0);
      __builtin_amdgcn_s_setprio(0);
    }
    asm volatile("s_barrier" ::: "memory");
  }
#undef TSTAGE6

  const int orow = row0 + wm * 64 + quad * 4;
  const int ocol = col0 + wn * 64 + lm;
#pragma unroll
  for (int mi = 0; mi < 4; mi++)
#pragma unroll
    for (int ni = 0; ni < 4; ni++)
#pragma unroll
      for (int r = 0; r < 4; r++)
        __builtin_nontemporal_store(
            acc[mi][ni][r],
            out + (size_t)(orow + mi * 16 + r) * H_N + ocol + ni * 16);
}

extern "C" void kernel_launch(void* const* d_in, const int* in_sizes, int n_in,
                              void* d_out, int out_size, void* d_ws,
                              size_t ws_size, hipStream_t stream) {
  (void)in_sizes; (void)n_in; (void)out_size;
  const float* hiddens = (const float*)d_in[0];
  const int* bsz = (const int*)d_in[1];
  const float* w1 = (const float*)d_in[2];
  const float* w2 = (const float*)d_in[3];
  float* out = (float*)d_out;

  // workspace layout (MiB): w1b 0:64 | w2t 64:128 | xb 128:144 | mt 144:160
  //                       | mtp (f32 split-K partials, x2) 160:224
  char* ws = (char*)d_ws;
  u16* w1b = (u16*)(ws);
  u16* w2t = (u16*)(ws + (size_t)64 * 1024 * 1024);
  u16* xb  = (u16*)(ws + (size_t)128 * 1024 * 1024);
  u16* mt  = (u16*)(ws + (size_t)144 * 1024 * 1024);
  float* mtp = (float*)(ws + (size_t)160 * 1024 * 1024);
  const size_t MiB = 1024 * 1024;

  // fused pre-pass: bf16 conversions (+ W2 transpose), nt source loads
  prepass_kernel<<<dim3(NB_W1 + NB_X + NB_TR), 256, 0, stream>>>(
      w1, hiddens, w2, w1b, xb, w2t);

  // M^T per expert
  if (ws_size >= 224 * MiB) {
    wgemm8_kernel<<<dim3(256), 512, 0, stream>>>(w2t, w1b, mtp);
    reduce_mt_kernel<2><<<dim3(4096), 256, 0, stream>>>(mtp, mt);
  } else {
    wgemm_kernel<<<dim3(512), 256, 0, stream>>>(w2t, w1b, mt);
  }

  // down = x @ M  (128x256 tiles -> 256 blocks, deep-pipelined)
  tgemm8_kernel<<<dim3(256), 512, 0, stream>>>(xb, bsz, mt, out);
}